// Round 4
// baseline (1132.592 us; speedup 1.0000x reference)
//
#include <hip/hip_runtime.h>

typedef __attribute__((ext_vector_type(8))) _Float16 half8;
typedef __attribute__((ext_vector_type(4))) float floatx4;

#define SEQ   2048
#define DIN   4096
#define NOUT  11008
#define KTOK  2201
#define NCORE 4403

__device__ __forceinline__ unsigned pk2(float a, float b) {
  auto h = __builtin_amdgcn_cvt_pkrtz(a, b);  // exact: values are f16-origin
  return __builtin_bit_cast(unsigned, h);
}
// monotone map: f32 bits -> ascending-ordered u32 key
__device__ __forceinline__ unsigned fkey32(unsigned u) {
  return u ^ ((u >> 31) ? 0xFFFFFFFFu : 0x80000000u);
}

// ---------------- GEMM: C[m][n] = sum_k X[m][k]*W[n][k] + bias[n] (f32 io, f16 MFMA) ----
__global__ __launch_bounds__(256) void gemm_bias(const float* __restrict__ X,
                                                 const float* __restrict__ W,
                                                 const float* __restrict__ Bias,
                                                 float* __restrict__ C) {
  __shared__ __attribute__((aligned(16))) unsigned short As[128 * 32];
  __shared__ __attribute__((aligned(16))) unsigned short Bs[128 * 32];
  const int t = threadIdx.x;
  const int m0 = blockIdx.y * 128, n0 = blockIdx.x * 128;
  const int l = t & 63, w = t >> 6;
  const int r = l & 15, q = l >> 4;
  const int wm = (w >> 1) * 64, wn = (w & 1) * 64;

  // staging map: thread t covers tile row t>>2 (and +64), k-cols (t&3)*8..+8
  const float* Ag = X + (size_t)(m0 + (t >> 2)) * DIN + (t & 3) * 8;
  const float* Bg = W + (size_t)(n0 + (t >> 2)) * DIN + (t & 3) * 8;
  unsigned short* la = As + t * 8;
  unsigned short* lb = Bs + t * 8;

  floatx4 acc[4][4] = {};
  const unsigned short* pa = As + (wm + r) * 32 + q * 8;
  const unsigned short* pb = Bs + (wn + r) * 32 + q * 8;

  for (int kt = 0; kt < DIN; kt += 32) {
    float4 a0 = *(const float4*)(Ag + kt);
    float4 a1 = *(const float4*)(Ag + kt + 4);
    float4 a2 = *(const float4*)(Ag + kt + 64 * DIN);
    float4 a3 = *(const float4*)(Ag + kt + 64 * DIN + 4);
    float4 b0 = *(const float4*)(Bg + kt);
    float4 b1 = *(const float4*)(Bg + kt + 4);
    float4 b2 = *(const float4*)(Bg + kt + 64 * DIN);
    float4 b3 = *(const float4*)(Bg + kt + 64 * DIN + 4);
    uint4 ua  = {pk2(a0.x, a0.y), pk2(a0.z, a0.w), pk2(a1.x, a1.y), pk2(a1.z, a1.w)};
    uint4 ua2 = {pk2(a2.x, a2.y), pk2(a2.z, a2.w), pk2(a3.x, a3.y), pk2(a3.z, a3.w)};
    uint4 ub  = {pk2(b0.x, b0.y), pk2(b0.z, b0.w), pk2(b1.x, b1.y), pk2(b1.z, b1.w)};
    uint4 ub2 = {pk2(b2.x, b2.y), pk2(b2.z, b2.w), pk2(b3.x, b3.y), pk2(b3.z, b3.w)};
    *(uint4*)la = ua;
    *(uint4*)(la + 2048) = ua2;
    *(uint4*)lb = ub;
    *(uint4*)(lb + 2048) = ub2;
    __syncthreads();
    half8 af[4];
#pragma unroll
    for (int im = 0; im < 4; ++im)
      af[im] = *(const half8*)(pa + im * 16 * 32);
#pragma unroll
    for (int in = 0; in < 4; ++in) {
      half8 bfv = *(const half8*)(pb + in * 16 * 32);
#pragma unroll
      for (int im = 0; im < 4; ++im)
        acc[im][in] = __builtin_amdgcn_mfma_f32_16x16x32_f16(af[im], bfv, acc[im][in], 0, 0, 0);
    }
    __syncthreads();
  }
  // epilogue: C/D layout col=lane&15, row=(lane>>4)*4+reg  [m89-verified]
#pragma unroll
  for (int in = 0; in < 4; ++in) {
    const int col = n0 + wn + in * 16 + r;
    const float bv = Bias[col];
#pragma unroll
    for (int im = 0; im < 4; ++im) {
      const int row = m0 + wm + im * 16 + q * 4;
#pragma unroll
      for (int i = 0; i < 4; ++i)
        C[(size_t)(row + i) * NOUT + col] = acc[im][in][i] + bv;
    }
  }
}

// ---------------- per-row exact top-KTOK membership -> counts (f32 keys) ----------------
// 3-pass radix (11/11/10 bits); ties at threshold taken in ascending index order.
__global__ __launch_bounds__(256) void row_topk(const float* __restrict__ TV,
                                                int* __restrict__ counts) {
  __shared__ __attribute__((aligned(16))) unsigned keys[NOUT];
  __shared__ int hist[2048];
  __shared__ int csum[256];
  __shared__ int sh[2];
  __shared__ int wtot[4];
  __shared__ int carry;
  const int t = threadIdx.x;

  const uint4* src = (const uint4*)(TV + (size_t)blockIdx.x * NOUT);
  for (int i = t; i < NOUT / 4; i += 256) {
    uint4 v = src[i];
    keys[i * 4 + 0] = fkey32(v.x);
    keys[i * 4 + 1] = fkey32(v.y);
    keys[i * 4 + 2] = fkey32(v.z);
    keys[i * 4 + 3] = fkey32(v.w);
  }

  // ---- pass A: bits [31:21] ----
  for (int i = t; i < 2048; i += 256) hist[i] = 0;
  __syncthreads();
  for (int i = t; i < NOUT; i += 256) atomicAdd(&hist[keys[i] >> 21], 1);
  __syncthreads();
  { int s = 0; for (int j = 0; j < 8; ++j) s += hist[t * 8 + j]; csum[t] = s; }
  __syncthreads();
  if (t == 0) {
    int cum = 0;
    for (int c = 255; c >= 0; --c) {
      if (cum + csum[c] >= KTOK) {
        for (int v = c * 8 + 7; v >= c * 8; --v) {
          if (cum + hist[v] >= KTOK) { sh[0] = v; sh[1] = cum; break; }
          cum += hist[v];
        }
        break;
      }
      cum += csum[c];
    }
  }
  __syncthreads();
  const unsigned b1 = (unsigned)sh[0];
  const int above1 = sh[1];
  __syncthreads();

  // ---- pass B: bits [20:10] among prefix==b1 ----
  for (int i = t; i < 2048; i += 256) hist[i] = 0;
  __syncthreads();
  for (int i = t; i < NOUT; i += 256) {
    unsigned k = keys[i];
    if ((k >> 21) == b1) atomicAdd(&hist[(k >> 10) & 0x7FF], 1);
  }
  __syncthreads();
  { int s = 0; for (int j = 0; j < 8; ++j) s += hist[t * 8 + j]; csum[t] = s; }
  __syncthreads();
  if (t == 0) {
    int cum = above1;
    for (int c = 255; c >= 0; --c) {
      if (cum + csum[c] >= KTOK) {
        for (int v = c * 8 + 7; v >= c * 8; --v) {
          if (cum + hist[v] >= KTOK) { sh[0] = v; sh[1] = cum; break; }
          cum += hist[v];
        }
        break;
      }
      cum += csum[c];
    }
  }
  __syncthreads();
  const unsigned b2 = (unsigned)sh[0];
  const int above2 = sh[1];
  const unsigned pref2 = (b1 << 11) | b2;
  __syncthreads();

  // ---- pass C: bits [9:0] among prefix==pref2 ----
  for (int i = t; i < 2048; i += 256) hist[i] = 0;
  __syncthreads();
  for (int i = t; i < NOUT; i += 256) {
    unsigned k = keys[i];
    if ((k >> 10) == pref2) atomicAdd(&hist[k & 0x3FF], 1);
  }
  __syncthreads();
  { int s = 0; for (int j = 0; j < 8; ++j) s += hist[t * 8 + j]; csum[t] = s; }
  __syncthreads();
  if (t == 0) {
    int cum = above2;
    for (int c = 255; c >= 0; --c) {
      if (cum + csum[c] >= KTOK) {
        for (int v = c * 8 + 7; v >= c * 8; --v) {
          if (cum + hist[v] >= KTOK) { sh[0] = v; sh[1] = cum; break; }
          cum += hist[v];
        }
        break;
      }
      cum += csum[c];
    }
    carry = 0;
  }
  __syncthreads();
  const unsigned T = (pref2 << 10) | (unsigned)sh[0];
  const int need = KTOK - sh[1];  // ties at T taken in ascending index order

  const int lane = t & 63, wv = t >> 6;
  for (int c0 = 0; c0 < NOUT; c0 += 256) {
    const int i = c0 + t;
    const unsigned k = keys[i];
    const bool gt = (k > T), eq = (k == T);
    unsigned long long m = __ballot(eq);
    if (lane == 0) wtot[wv] = __popcll(m);
    __syncthreads();
    int rank = carry + __popcll(m & ((1ULL << lane) - 1));
    for (int ww = 0; ww < wv; ++ww) rank += wtot[ww];
    if (gt || (eq && rank < need)) atomicAdd(&counts[i], 1);
    const int tot = wtot[0] + wtot[1] + wtot[2] + wtot[3];
    __syncthreads();
    if (t == 0) carry += tot;
  }
}

// ---------------- top-NCORE of counts (ties: lower index), emit in index order ----------
__global__ __launch_bounds__(256) void select_core(const int* __restrict__ counts,
                                                   const float* __restrict__ Bias,
                                                   int* __restrict__ core_idx,
                                                   float* __restrict__ bias_out) {
  __shared__ int cl[NOUT];
  __shared__ int hist[2052];
  __shared__ int sh[2];
  __shared__ int wt_eq[4], wt_sel[4];
  __shared__ int carry_eq, carry_sel;
  const int t = threadIdx.x;
  for (int i = t; i < NOUT; i += 256) cl[i] = counts[i];
  for (int i = t; i < 2052; i += 256) hist[i] = 0;
  __syncthreads();
  for (int i = t; i < NOUT; i += 256) atomicAdd(&hist[cl[i]], 1);
  __syncthreads();
  if (t == 0) {
    int cum = 0;
    for (int v = 2048; v >= 0; --v) {
      int c = hist[v];
      if (cum + c >= NCORE) { sh[0] = v; sh[1] = NCORE - cum; break; }
      cum += c;
    }
    carry_eq = 0; carry_sel = 0;
  }
  __syncthreads();
  const int Cv = sh[0], need2 = sh[1];
  const int lane = t & 63, wv = t >> 6;
  for (int c0 = 0; c0 < NOUT; c0 += 256) {
    const int i = c0 + t;
    const int cnt = cl[i];
    const bool gt = (cnt > Cv), eq = (cnt == Cv);
    unsigned long long meq = __ballot(eq);
    const int eqpre = __popcll(meq & ((1ULL << lane) - 1));
    if (lane == 0) wt_eq[wv] = __popcll(meq);
    __syncthreads();
    int eqrank = carry_eq + eqpre;
    for (int ww = 0; ww < wv; ++ww) eqrank += wt_eq[ww];
    const bool sel = gt || (eq && eqrank < need2);
    unsigned long long msel = __ballot(sel);
    const int selpre = __popcll(msel & ((1ULL << lane) - 1));
    if (lane == 0) wt_sel[wv] = __popcll(msel);
    __syncthreads();  // barrier between wt_sel write and read
    int pos = carry_sel + selpre;
    for (int ww = 0; ww < wv; ++ww) pos += wt_sel[ww];
    if (sel) { core_idx[pos] = i; bias_out[pos] = Bias[i]; }
    const int te = wt_eq[0] + wt_eq[1] + wt_eq[2] + wt_eq[3];
    const int ts = wt_sel[0] + wt_sel[1] + wt_sel[2] + wt_sel[3];
    __syncthreads();
    if (t == 0) { carry_eq += te; carry_sel += ts; }
  }
}

// ---------------- gather selected weight rows (f32) ----------------
__global__ __launch_bounds__(256) void gather_rows(const float* __restrict__ W,
                                                   const int* __restrict__ core_idx,
                                                   float* __restrict__ outW) {
  const int b = blockIdx.x;
  const int j = core_idx[b];
  const float4* src = (const float4*)(W + (size_t)j * DIN);
  float4* dst = (float4*)(outW + (size_t)b * DIN);
  for (int i = threadIdx.x; i < DIN / 4; i += 256) dst[i] = src[i];
}

__global__ __launch_bounds__(256) void zero_counts(int* __restrict__ counts) {
  counts[blockIdx.x * 256 + threadIdx.x] = 0;
}

extern "C" void kernel_launch(void* const* d_in, const int* in_sizes, int n_in,
                              void* d_out, int out_size, void* d_ws, size_t ws_size,
                              hipStream_t stream) {
  const float* X    = (const float*)d_in[0];
  const float* W    = (const float*)d_in[1];
  const float* Bias = (const float*)d_in[2];
  float* out_tv = (float*)d_out;
  float* out_w  = out_tv + (size_t)SEQ * NOUT;
  float* out_b  = out_w + (size_t)NCORE * DIN;
  int* counts   = (int*)d_ws;
  int* core_idx = counts + NOUT;

  zero_counts<<<NOUT / 256, 256, 0, stream>>>(counts);
  gemm_bias<<<dim3(NOUT / 128, SEQ / 128), 256, 0, stream>>>(X, W, Bias, out_tv);
  row_topk<<<SEQ, 256, 0, stream>>>(out_tv, counts);
  select_core<<<1, 256, 0, stream>>>(counts, Bias, core_idx, out_b);
  gather_rows<<<NCORE, 256, 0, stream>>>(W, core_idx, out_w);
}

// Round 5
// 791.365 us; speedup vs baseline: 1.4312x; 1.4312x over previous
//
#include <hip/hip_runtime.h>

typedef __attribute__((ext_vector_type(8))) _Float16 half8;
typedef __attribute__((ext_vector_type(4))) float floatx4;
typedef unsigned short us_t;

#define SEQ   2048
#define DIN   4096
#define NOUT  11008
#define KTOK  2201
#define NCORE 4403
#define NCHUNK 43   /* NOUT / 256 */

__device__ __forceinline__ unsigned pk2(float a, float b) {
  auto h = __builtin_amdgcn_cvt_pkrtz(a, b);  // exact: values are f16-origin
  return __builtin_bit_cast(unsigned, h);
}
// monotone map: f32 bits -> ascending-ordered u32 key
__device__ __forceinline__ unsigned fkey32(unsigned u) {
  return u ^ ((u >> 31) ? 0xFFFFFFFFu : 0x80000000u);
}
__device__ __forceinline__ void gl2lds16(const us_t* g, us_t* l) {
  __builtin_amdgcn_global_load_lds(
      (const __attribute__((address_space(1))) unsigned int*)(g),
      (__attribute__((address_space(3))) unsigned int*)(l), 16, 0, 0);
}

// ---------------- f32 -> f16 conversion (8 elems/thread) ----------------
__global__ __launch_bounds__(256) void cvt_f16(const float* __restrict__ src,
                                               unsigned* __restrict__ dst, int n8) {
  int i = blockIdx.x * 256 + threadIdx.x;
  if (i >= n8) return;
  const float4* s = (const float4*)src + (size_t)i * 2;
  float4 a = s[0], b = s[1];
  uint4 o = {pk2(a.x, a.y), pk2(a.z, a.w), pk2(b.x, b.y), pk2(b.z, b.w)};
  ((uint4*)dst)[i] = o;
}

// ---------------- fast GEMM: f16 inputs via global_load_lds (m97 structure) ----------
__global__ __launch_bounds__(256) void gemm_f16(const us_t* __restrict__ X16,
                                                const us_t* __restrict__ W16,
                                                const float* __restrict__ Bias,
                                                float* __restrict__ C) {
  __shared__ __attribute__((aligned(16))) us_t As[128 * 32];
  __shared__ __attribute__((aligned(16))) us_t Bs[128 * 32];
  const int t = threadIdx.x;
  const int m0 = blockIdx.y * 128, n0 = blockIdx.x * 128;
  const int l = t & 63, w = t >> 6;
  const int r = l & 15, q = l >> 4;
  const int wm = (w >> 1) * 64, wn = (w & 1) * 64;

  const us_t* Ag = X16 + (size_t)(m0 + (t >> 2)) * DIN + (t & 3) * 8;
  const us_t* Bg = W16 + (size_t)(n0 + (t >> 2)) * DIN + (t & 3) * 8;
  us_t* la = As + t * 8;
  us_t* lb = Bs + t * 8;

  floatx4 acc[4][4] = {};
  const us_t* pa = As + (wm + r) * 32 + q * 8;
  const us_t* pb = Bs + (wn + r) * 32 + q * 8;

  for (int kt = 0; kt < DIN; kt += 32) {
    gl2lds16(Ag + kt, la);
    gl2lds16(Ag + kt + 64 * DIN, la + 2048);
    gl2lds16(Bg + kt, lb);
    gl2lds16(Bg + kt + 64 * DIN, lb + 2048);
    __syncthreads();
    half8 af[4];
#pragma unroll
    for (int im = 0; im < 4; ++im)
      af[im] = *(const half8*)(pa + im * 16 * 32);
#pragma unroll
    for (int in = 0; in < 4; ++in) {
      half8 bfv = *(const half8*)(pb + in * 16 * 32);
#pragma unroll
      for (int im = 0; im < 4; ++im)
        acc[im][in] = __builtin_amdgcn_mfma_f32_16x16x32_f16(af[im], bfv, acc[im][in], 0, 0, 0);
    }
    __syncthreads();
  }
#pragma unroll
  for (int in = 0; in < 4; ++in) {
    const int col = n0 + wn + in * 16 + r;
    const float bv = Bias[col];
#pragma unroll
    for (int im = 0; im < 4; ++im) {
      const int row = m0 + wm + im * 16 + q * 4;
#pragma unroll
      for (int i = 0; i < 4; ++i)
        C[(size_t)(row + i) * NOUT + col] = acc[im][in][i] + bv;
    }
  }
}

// ---------------- fallback GEMM (f32 staging, round-4 verified) ----------------
__global__ __launch_bounds__(256) void gemm_bias(const float* __restrict__ X,
                                                 const float* __restrict__ W,
                                                 const float* __restrict__ Bias,
                                                 float* __restrict__ C) {
  __shared__ __attribute__((aligned(16))) us_t As[128 * 32];
  __shared__ __attribute__((aligned(16))) us_t Bs[128 * 32];
  const int t = threadIdx.x;
  const int m0 = blockIdx.y * 128, n0 = blockIdx.x * 128;
  const int l = t & 63, w = t >> 6;
  const int r = l & 15, q = l >> 4;
  const int wm = (w >> 1) * 64, wn = (w & 1) * 64;
  const float* Ag = X + (size_t)(m0 + (t >> 2)) * DIN + (t & 3) * 8;
  const float* Bg = W + (size_t)(n0 + (t >> 2)) * DIN + (t & 3) * 8;
  us_t* la = As + t * 8;
  us_t* lb = Bs + t * 8;
  floatx4 acc[4][4] = {};
  const us_t* pa = As + (wm + r) * 32 + q * 8;
  const us_t* pb = Bs + (wn + r) * 32 + q * 8;
  for (int kt = 0; kt < DIN; kt += 32) {
    float4 a0 = *(const float4*)(Ag + kt);
    float4 a1 = *(const float4*)(Ag + kt + 4);
    float4 a2 = *(const float4*)(Ag + kt + 64 * DIN);
    float4 a3 = *(const float4*)(Ag + kt + 64 * DIN + 4);
    float4 b0 = *(const float4*)(Bg + kt);
    float4 b1 = *(const float4*)(Bg + kt + 4);
    float4 b2 = *(const float4*)(Bg + kt + 64 * DIN);
    float4 b3 = *(const float4*)(Bg + kt + 64 * DIN + 4);
    uint4 ua  = {pk2(a0.x, a0.y), pk2(a0.z, a0.w), pk2(a1.x, a1.y), pk2(a1.z, a1.w)};
    uint4 ua2 = {pk2(a2.x, a2.y), pk2(a2.z, a2.w), pk2(a3.x, a3.y), pk2(a3.z, a3.w)};
    uint4 ub  = {pk2(b0.x, b0.y), pk2(b0.z, b0.w), pk2(b1.x, b1.y), pk2(b1.z, b1.w)};
    uint4 ub2 = {pk2(b2.x, b2.y), pk2(b2.z, b2.w), pk2(b3.x, b3.y), pk2(b3.z, b3.w)};
    *(uint4*)la = ua;
    *(uint4*)(la + 2048) = ua2;
    *(uint4*)lb = ub;
    *(uint4*)(lb + 2048) = ub2;
    __syncthreads();
    half8 af[4];
#pragma unroll
    for (int im = 0; im < 4; ++im)
      af[im] = *(const half8*)(pa + im * 16 * 32);
#pragma unroll
    for (int in = 0; in < 4; ++in) {
      half8 bfv = *(const half8*)(pb + in * 16 * 32);
#pragma unroll
      for (int im = 0; im < 4; ++im)
        acc[im][in] = __builtin_amdgcn_mfma_f32_16x16x32_f16(af[im], bfv, acc[im][in], 0, 0, 0);
    }
    __syncthreads();
  }
#pragma unroll
  for (int in = 0; in < 4; ++in) {
    const int col = n0 + wn + in * 16 + r;
    const float bv = Bias[col];
#pragma unroll
    for (int im = 0; im < 4; ++im) {
      const int row = m0 + wm + im * 16 + q * 4;
#pragma unroll
      for (int i = 0; i < 4; ++i)
        C[(size_t)(row + i) * NOUT + col] = acc[im][in][i] + bv;
    }
  }
}

// ---------------- per-row exact top-KTOK membership -> counts ----------------
__global__ __launch_bounds__(256) void row_topk(const float* __restrict__ TV,
                                                int* __restrict__ counts) {
  __shared__ __attribute__((aligned(16))) unsigned keys[NOUT];
  __shared__ int hist[2048];
  __shared__ int csum[256];
  __shared__ int shv[2];
  __shared__ int cnte[NCHUNK * 4];
  const int t = threadIdx.x;
  const int lane = t & 63, wv = t >> 6;

  for (int i = t; i < 2048; i += 256) hist[i] = 0;
  __syncthreads();
  // fused: load + key + pass-A histogram (bits [31:21])
  const uint4* src = (const uint4*)(TV + (size_t)blockIdx.x * NOUT);
  for (int i = t; i < NOUT / 4; i += 256) {
    uint4 v = src[i];
    unsigned k0 = fkey32(v.x), k1 = fkey32(v.y), k2 = fkey32(v.z), k3 = fkey32(v.w);
    uint4 kk = {k0, k1, k2, k3};
    *(uint4*)&keys[i * 4] = kk;
    atomicAdd(&hist[k0 >> 21], 1);
    atomicAdd(&hist[k1 >> 21], 1);
    atomicAdd(&hist[k2 >> 21], 1);
    atomicAdd(&hist[k3 >> 21], 1);
  }
  __syncthreads();
  { int s = 0; for (int j = 0; j < 8; ++j) s += hist[t * 8 + j]; csum[t] = s; }
  __syncthreads();
  if (t == 0) {
    int cum = 0;
    for (int c = 255; c >= 0; --c) {
      if (cum + csum[c] >= KTOK) {
        for (int v = c * 8 + 7; v >= c * 8; --v) {
          if (cum + hist[v] >= KTOK) { shv[0] = v; shv[1] = cum; break; }
          cum += hist[v];
        }
        break;
      }
      cum += csum[c];
    }
  }
  __syncthreads();
  const unsigned b1 = (unsigned)shv[0];
  const int above1 = shv[1];
  __syncthreads();

  // pass B: bits [20:10] among prefix==b1
  for (int i = t; i < 2048; i += 256) hist[i] = 0;
  __syncthreads();
  for (int i = t; i < NOUT; i += 256) {
    unsigned k = keys[i];
    if ((k >> 21) == b1) atomicAdd(&hist[(k >> 10) & 0x7FF], 1);
  }
  __syncthreads();
  { int s = 0; for (int j = 0; j < 8; ++j) s += hist[t * 8 + j]; csum[t] = s; }
  __syncthreads();
  if (t == 0) {
    int cum = above1;
    for (int c = 255; c >= 0; --c) {
      if (cum + csum[c] >= KTOK) {
        for (int v = c * 8 + 7; v >= c * 8; --v) {
          if (cum + hist[v] >= KTOK) { shv[0] = v; shv[1] = cum; break; }
          cum += hist[v];
        }
        break;
      }
      cum += csum[c];
    }
  }
  __syncthreads();
  const unsigned b2 = (unsigned)shv[0];
  const int above2 = shv[1];
  const unsigned pref2 = (b1 << 11) | b2;
  __syncthreads();

  // pass C: bits [9:0] among prefix==pref2
  for (int i = t; i < 1024; i += 256) hist[i] = 0;
  __syncthreads();
  for (int i = t; i < NOUT; i += 256) {
    unsigned k = keys[i];
    if ((k >> 10) == pref2) atomicAdd(&hist[k & 0x3FF], 1);
  }
  __syncthreads();
  { int s = 0; if (t < 128) { for (int j = 0; j < 8; ++j) s += hist[t * 8 + j]; } csum[t] = s; }
  __syncthreads();
  if (t == 0) {
    int cum = above2;
    for (int c = 127; c >= 0; --c) {
      if (cum + csum[c] >= KTOK) {
        for (int v = c * 8 + 7; v >= c * 8; --v) {
          if (cum + hist[v] >= KTOK) { shv[0] = v; shv[1] = cum; break; }
          cum += hist[v];
        }
        break;
      }
      cum += csum[c];
    }
  }
  __syncthreads();
  const unsigned T = (pref2 << 10) | (unsigned)shv[0];
  const int need = KTOK - shv[1];  // ties at T: ascending index order

  // membership sweep 1 (barrier-free): gt adds + per-(chunk,wave) eq counts
  for (int c = 0; c < NCHUNK; ++c) {
    const int i = c * 256 + t;
    const unsigned k = keys[i];
    if (k > T) atomicAdd(&counts[i], 1);
    unsigned long long me = __ballot(k == T);
    if (lane == 0) cnte[c * 4 + wv] = __popcll(me);
  }
  __syncthreads();
  // sweep 2: eq-rank resolution (eq elements rare; prefix computed on demand)
  for (int c = 0; c < NCHUNK; ++c) {
    const int i = c * 256 + t;
    const unsigned k = keys[i];
    const bool eq = (k == T);
    unsigned long long me = __ballot(eq);
    if (eq) {
      int rank = __popcll(me & ((1ULL << lane) - 1));
      const int idx = c * 4 + wv;
      for (int j = 0; j < idx; ++j) rank += cnte[j];
      if (rank < need) atomicAdd(&counts[i], 1);
    }
  }
}

// ---------------- top-NCORE of counts (ties: lower index), emit in index order --------
__global__ __launch_bounds__(256) void select_core(const int* __restrict__ counts,
                                                   const float* __restrict__ Bias,
                                                   int* __restrict__ core_idx,
                                                   float* __restrict__ bias_out) {
  __shared__ int cl[NOUT];
  __shared__ int hist[2049];
  __shared__ int csum[257];
  __shared__ int shv[2];
  __shared__ int tabS[256];  // packed (gt | eq<<16) per (chunk,wave)
  const int t = threadIdx.x;
  const int lane = t & 63, wv = t >> 6;
  for (int i = t; i < NOUT; i += 256) cl[i] = counts[i];
  for (int i = t; i < 2049; i += 256) hist[i] = 0;
  tabS[t] = 0;
  __syncthreads();
  for (int i = t; i < NOUT; i += 256) atomicAdd(&hist[cl[i]], 1);
  __syncthreads();
  { int s = 0; for (int j = 0; j < 8; ++j) s += hist[t * 8 + j]; csum[t] = s;
    if (t == 0) csum[256] = hist[2048]; }
  __syncthreads();
  if (t == 0) {
    int cum = 0;
    for (int c = 256; c >= 0; --c) {
      if (cum + csum[c] >= NCORE) {
        int hi = (c == 256) ? 2048 : c * 8 + 7;
        for (int v = hi; v >= c * 8; --v) {
          if (cum + hist[v] >= NCORE) { shv[0] = v; shv[1] = NCORE - cum; break; }
          cum += hist[v];
        }
        break;
      }
      cum += csum[c];
    }
  }
  __syncthreads();
  const int Cv = shv[0], need2 = shv[1];
  // sweep 1: per-(chunk,wave) ballot counts (no barriers)
  for (int c = 0; c < NCHUNK; ++c) {
    const int i = c * 256 + t;
    const int cnt = cl[i];
    unsigned long long mg = __ballot(cnt > Cv);
    unsigned long long me = __ballot(cnt == Cv);
    if (lane == 0) tabS[c * 4 + wv] = __popcll(mg) | (__popcll(me) << 16);
  }
  __syncthreads();
  // packed inclusive Hillis-Steele scan -> exclusive prefix
  int orig = tabS[t];
  for (int off = 1; off < 256; off <<= 1) {
    int v = (t >= off) ? tabS[t - off] : 0;
    __syncthreads();
    tabS[t] += v;
    __syncthreads();
  }
  int excl = tabS[t] - orig;
  __syncthreads();
  tabS[t] = excl;
  __syncthreads();
  // sweep 2: compute position, emit
  const unsigned long long lm = (1ULL << lane) - 1;
  for (int c = 0; c < NCHUNK; ++c) {
    const int i = c * 256 + t;
    const int cnt = cl[i];
    const bool g = cnt > Cv, e = cnt == Cv;
    unsigned long long mg = __ballot(g);
    unsigned long long me = __ballot(e);
    const int P = tabS[c * 4 + wv];
    const int gpre = (P & 0xFFFF) + __popcll(mg & lm);
    const int epre = (P >> 16) + __popcll(me & lm);
    const bool sel = g || (e && epre < need2);
    if (sel) {
      const int pos = gpre + (epre < need2 ? epre : need2);
      core_idx[pos] = i;
      bias_out[pos] = Bias[i];
    }
  }
}

// ---------------- gather selected weight rows (f32) ----------------
__global__ __launch_bounds__(256) void gather_rows(const float* __restrict__ W,
                                                   const int* __restrict__ core_idx,
                                                   float* __restrict__ outW) {
  const int b = blockIdx.x;
  const int j = core_idx[b];
  const float4* src = (const float4*)(W + (size_t)j * DIN);
  float4* dst = (float4*)(outW + (size_t)b * DIN);
  for (int i = threadIdx.x; i < DIN / 4; i += 256) dst[i] = src[i];
}

__global__ __launch_bounds__(256) void zero_counts(int* __restrict__ counts) {
  counts[blockIdx.x * 256 + threadIdx.x] = 0;
}

extern "C" void kernel_launch(void* const* d_in, const int* in_sizes, int n_in,
                              void* d_out, int out_size, void* d_ws, size_t ws_size,
                              hipStream_t stream) {
  const float* X    = (const float*)d_in[0];
  const float* W    = (const float*)d_in[1];
  const float* Bias = (const float*)d_in[2];
  float* out_tv = (float*)d_out;
  float* out_w  = out_tv + (size_t)SEQ * NOUT;
  float* out_b  = out_w + (size_t)NCORE * DIN;
  int* counts   = (int*)d_ws;
  int* core_idx = counts + NOUT;

  const size_t meta = 64 * 1024;
  const size_t need_ws = meta + ((size_t)SEQ * DIN + (size_t)NOUT * DIN) * sizeof(us_t);

  zero_counts<<<NOUT / 256, 256, 0, stream>>>(counts);
  if (ws_size >= need_ws) {
    us_t* X16 = (us_t*)((char*)d_ws + meta);
    us_t* W16 = X16 + (size_t)SEQ * DIN;
    cvt_f16<<<(SEQ * DIN / 8 + 255) / 256, 256, 0, stream>>>(X, (unsigned*)X16, SEQ * DIN / 8);
    cvt_f16<<<(NOUT * DIN / 8 + 255) / 256, 256, 0, stream>>>(W, (unsigned*)W16, NOUT * DIN / 8);
    gemm_f16<<<dim3(NOUT / 128, SEQ / 128), 256, 0, stream>>>(X16, W16, Bias, out_tv);
  } else {
    gemm_bias<<<dim3(NOUT / 128, SEQ / 128), 256, 0, stream>>>(X, W, Bias, out_tv);
  }
  row_topk<<<SEQ, 256, 0, stream>>>(out_tv, counts);
  select_core<<<1, 256, 0, stream>>>(counts, Bias, core_idx, out_b);
  gather_rows<<<NCORE, 256, 0, stream>>>(W, core_idx, out_w);
}